// Round 9
// baseline (101.127 us; speedup 1.0000x reference)
//
#include <hip/hip_runtime.h>
#include <hip/hip_bf16.h>

typedef __attribute__((ext_vector_type(8))) short bf16x8;
typedef __attribute__((ext_vector_type(4))) float f32x4;
typedef __attribute__((ext_vector_type(16))) float f32x16;

static __device__ __forceinline__ unsigned short f2bf(float f) {
  union { float f; unsigned int u; } v; v.f = f;
  unsigned int u = v.u;
  return (unsigned short)((u + 0x7FFFu + ((u >> 16) & 1u)) >> 16);
}

// fp32 -> bf16, writing MFMA-fragment-tiled layouts:
// x -> A4 [m/16][k/32][16][32]; Wk/Wq/Wv -> B4 (rows 0..2303, Wq scaled); Wo -> B4.
__global__ __launch_bounds__(256) void cvt_all(
    const float* __restrict__ x, const float* __restrict__ wk,
    const float* __restrict__ wq, const float* __restrict__ wv,
    const float* __restrict__ wo,
    unsigned short* __restrict__ x4, unsigned short* __restrict__ wkqv4,
    unsigned short* __restrict__ wo4) {
  int i = blockIdx.x * 256 + threadIdx.x;
  int e0 = i * 4;
  const float* src;
  unsigned short* dst;
  int m, k, srcoff;
  float scale = 1.0f;
  if (e0 < 3145728) {
    src = x; srcoff = e0; m = e0 / 768; k = e0 - m * 768; dst = x4;
  } else {
    int j = e0 - 3145728;
    int a = j / 589824;
    int off = j - a * 589824;
    int nl = off / 768;
    k = off - nl * 768;
    srcoff = off;
    if (a == 0)      { src = wk; m = nl;        dst = wkqv4; }
    else if (a == 1) { src = wq; m = 768 + nl;  dst = wkqv4; scale = 0.18033688011112042f; }
    else if (a == 2) { src = wv; m = 1536 + nl; dst = wkqv4; }
    else             { src = wo; m = nl;        dst = wo4; }
  }
  float4 v = *(const float4*)(src + srcoff);
  long idx = ((long)(m >> 4) * 24 + (k >> 5)) * 512 + (m & 15) * 32 + (k & 31);
  ushort4 r;
  r.x = f2bf(v.x * scale); r.y = f2bf(v.y * scale);
  r.z = f2bf(v.z * scale); r.w = f2bf(v.w * scale);
  *(ushort4*)(dst + idx) = r;
}

// register-direct 128x128 tile GEMM, K=768, zero LDS / zero barriers.
// A4/B4 tiled operands -> every fragment load is a dense 1KB wave-read.
// MODE 0: fused QKV epilogue (N=2304 -> K4 tiled / qb [B,H,P,64] / V4 tiled)
// MODE 1: fp32 linear out (N=768)
template <int MODE>
__device__ __forceinline__ void gemm_rd_body(
    const unsigned short* __restrict__ A4,
    const unsigned short* __restrict__ B4,
    void* __restrict__ outK, void* __restrict__ outQ, void* __restrict__ outV,
    int m0, int n0) {
  const int tid = threadIdx.x;
  const int w = tid >> 6;
  const int l = tid & 63;
  const int g = l >> 4;
  const int c = l & 15;
  const int wr = w >> 1, wc = w & 1;
  const int laneoff = c * 32 + g * 8;

  const unsigned short* pA0 = A4 + (long)((m0 >> 4) + wr * 4 + 0) * 12288 + laneoff;
  const unsigned short* pA1 = A4 + (long)((m0 >> 4) + wr * 4 + 1) * 12288 + laneoff;
  const unsigned short* pA2 = A4 + (long)((m0 >> 4) + wr * 4 + 2) * 12288 + laneoff;
  const unsigned short* pA3 = A4 + (long)((m0 >> 4) + wr * 4 + 3) * 12288 + laneoff;
  const unsigned short* pB0 = B4 + (long)((n0 >> 4) + wc * 4 + 0) * 12288 + laneoff;
  const unsigned short* pB1 = B4 + (long)((n0 >> 4) + wc * 4 + 1) * 12288 + laneoff;
  const unsigned short* pB2 = B4 + (long)((n0 >> 4) + wc * 4 + 2) * 12288 + laneoff;
  const unsigned short* pB3 = B4 + (long)((n0 >> 4) + wc * 4 + 3) * 12288 + laneoff;

  f32x4 acc[4][4];
#pragma unroll
  for (int i = 0; i < 4; i++)
#pragma unroll
    for (int j = 0; j < 4; j++) acc[i][j] = (f32x4){0.f, 0.f, 0.f, 0.f};

  bf16x8 aA[4], bA[4], aB[4], bB[4];

  auto load = [&](bf16x8* a, bf16x8* b, int kb) {
    const int o = kb * 512;
    a[0] = *(const bf16x8*)(pA0 + o);
    a[1] = *(const bf16x8*)(pA1 + o);
    a[2] = *(const bf16x8*)(pA2 + o);
    a[3] = *(const bf16x8*)(pA3 + o);
    b[0] = *(const bf16x8*)(pB0 + o);
    b[1] = *(const bf16x8*)(pB1 + o);
    b[2] = *(const bf16x8*)(pB2 + o);
    b[3] = *(const bf16x8*)(pB3 + o);
  };
  auto comp = [&](const bf16x8* a, const bf16x8* b) {
    __builtin_amdgcn_s_setprio(1);
#pragma unroll
    for (int mi = 0; mi < 4; ++mi)
#pragma unroll
      for (int ni = 0; ni < 4; ++ni)
        acc[mi][ni] = __builtin_amdgcn_mfma_f32_16x16x32_bf16(a[mi], b[ni], acc[mi][ni], 0, 0, 0);
    __builtin_amdgcn_s_setprio(0);
  };

  load(aA, bA, 0);
  int kb = 0;
  while (kb + 2 < 24) {
    load(aB, bB, kb + 1);
    comp(aA, bA);
    load(aA, bA, kb + 2);
    comp(aB, bB);
    kb += 2;
  }
  load(aB, bB, 23);
  comp(aA, bA);
  comp(aB, bB);

  if (MODE == 1) {
    float* O = (float*)outK;
#pragma unroll
    for (int mi = 0; mi < 4; ++mi)
#pragma unroll
      for (int ni = 0; ni < 4; ++ni)
#pragma unroll
        for (int r = 0; r < 4; ++r) {
          int m = m0 + wr * 64 + mi * 16 + g * 4 + r;
          int n = n0 + wc * 64 + ni * 16 + c;
          O[(long)m * 768 + n] = acc[mi][ni][r];
        }
  } else {
    const int which = (n0 >= 1536) ? 2 : (n0 >= 768 ? 1 : 0);
    const int nb = n0 - which * 768;
#pragma unroll
    for (int mi = 0; mi < 4; ++mi)
#pragma unroll
      for (int ni = 0; ni < 4; ++ni)
#pragma unroll
        for (int r = 0; r < 4; ++r) {
          int m = m0 + wr * 64 + mi * 16 + g * 4 + r;
          int nn = nb + wc * 64 + ni * 16 + c;
          int b = m >> 11, p = m & 2047;
          int h = nn >> 6, e = nn & 63;
          unsigned short val = f2bf(acc[mi][ni][r]);
          long bh = b * 12 + h;
          if (which == 0) {
            // K4 tiled: [bh][p/32][d/16][p&31][d&15]
            long idx = bh * 131072 + (p >> 5) * 2048 + (e >> 4) * 512 + (p & 31) * 16 + (e & 15);
            ((unsigned short*)outK)[idx] = val;
          } else if (which == 1) {
            ((unsigned short*)outQ)[((bh * 2048 + p) << 6) + e] = val;
          } else {
            // V4 tiled: [bh][p/16][e][p&15]
            long idx = bh * 131072 + (p >> 4) * 1024 + e * 16 + (p & 15);
            ((unsigned short*)outV)[idx] = val;
          }
        }
  }
}

// grid 576 (1D). XCD-chunked: xcd = bid&7 owns 8m x 9n panel (3.3 MB, L2-fit)
__global__ __launch_bounds__(256) void gemm_qkv(
    const unsigned short* __restrict__ A4,
    const unsigned short* __restrict__ Wkqv4,
    unsigned short* __restrict__ k4b, unsigned short* __restrict__ qb,
    unsigned short* __restrict__ v4b) {
  const int lb = blockIdx.x;
  const int xcd = lb & 7, idx = lb >> 3;       // idx 0..71
  const int mg = xcd >> 1, ng = xcd & 1;
  const int mi = idx / 9, ni = idx - 9 * mi;   // ni fastest: share A-panel
  gemm_rd_body<0>(A4, Wkqv4, k4b, qb, v4b, (mg * 8 + mi) * 128, (ng * 9 + ni) * 128);
}

// grid 192 (1D). xcd = bid&7 owns 4m x 6n panel
__global__ __launch_bounds__(256) void gemm_out(
    const unsigned short* __restrict__ Z4,
    const unsigned short* __restrict__ Wo4,
    float* __restrict__ out) {
  const int lb = blockIdx.x;
  const int xcd = lb & 7, idx = lb >> 3;       // idx 0..23
  const int mi = idx / 6, ni = idx - 6 * mi;
  gemm_rd_body<1>(Z4, Wo4, out, nullptr, nullptr, (xcd * 4 + mi) * 128, ni * 128);
}

// causal flash attention: swapped QK^T (32x32x16), in-register softmax,
// split-k x4: block = 4 waves on ONE 32-row q-chunk; LPT dispatch.
// K4/V4 tiled operands; Z written in A4-tiled form for gemm_out.
__global__ __launch_bounds__(256) void attn(
    const unsigned short* __restrict__ Q,
    const unsigned short* __restrict__ K4,
    const unsigned short* __restrict__ V4,
    unsigned short* __restrict__ Z) {
  __shared__ float2 Opart[3][16][64];
  __shared__ float Lpart[3][32];
  __shared__ float Linv[32];
  const int bx = blockIdx.x;                   // 0..1535
  const int cidx = bx / 24;                    // 0..63
  const int bh = bx - cidx * 24;               // 0..23
  const int c = 63 - cidx;                     // LPT: big chunks dispatched first
  const int tid = threadIdx.x;
  const int w = tid >> 6;                      // kpar 0..3
  const int l = tid & 63;
  const int ql = l & 31;
  const int hi = l >> 5;
  const int b = bh / 12, hd = bh - b * 12;
  const long base = (long)bh * 2048 * 64;
  const int q0 = c * 32;

  bf16x8 qf[4];
  {
    const unsigned short* qp = Q + base + (long)(q0 + ql) * 64 + hi * 8;
#pragma unroll
    for (int d = 0; d < 4; ++d) qf[d] = *(const bf16x8*)(qp + d * 16);
  }

  f32x16 o0, o1;
#pragma unroll
  for (int r = 0; r < 16; ++r) { o0[r] = 0.f; o1[r] = 0.f; }
  float lsum = 0.f;

  const unsigned short* kp = K4 + (long)bh * 131072 + ql * 16 + hi * 8;
  const unsigned short* vp = V4 + (long)bh * 131072 + ql * 16 + hi * 8;

  auto loadsub = [&](bf16x8* kf, bf16x8* v0, bf16x8* v1, int s) {
    const unsigned short* kps = kp + (long)s * 2048;
#pragma unroll
    for (int d = 0; d < 4; ++d) kf[d] = *(const bf16x8*)(kps + d * 512);
    const unsigned short* vps = vp + (long)s * 2048;
    v0[0] = *(const bf16x8*)(vps);
    v0[1] = *(const bf16x8*)(vps + 1024);
    v1[0] = *(const bf16x8*)(vps + 512);
    v1[1] = *(const bf16x8*)(vps + 1536);
  };

  auto compute = [&](const bf16x8* kf, const bf16x8* v0, const bf16x8* v1, bool diag) {
    __builtin_amdgcn_s_setprio(1);
    f32x16 s_;
#pragma unroll
    for (int r = 0; r < 16; ++r) s_[r] = 0.f;
#pragma unroll
    for (int d = 0; d < 4; ++d)
      s_ = __builtin_amdgcn_mfma_f32_32x32x16_bf16(kf[d], qf[d], s_, 0, 0, 0);
    __builtin_amdgcn_s_setprio(0);
    if (diag) {
#pragma unroll
      for (int r = 0; r < 16; ++r) {
        int krow = (r & 3) + 8 * (r >> 2) + 4 * hi;
        s_[r] = (krow <= ql) ? s_[r] : -1e30f;
      }
    }
    float p[16];
#pragma unroll
    for (int r = 0; r < 16; ++r) { p[r] = exp2f(s_[r]); lsum += p[r]; }
    unsigned int wpk[8];
#pragma unroll
    for (int i = 0; i < 8; ++i)
      asm("v_cvt_pk_bf16_f32 %0, %1, %2" : "=v"(wpk[i]) : "v"(p[2 * i]), "v"(p[2 * i + 1]));
    asm volatile("v_permlane32_swap_b32 %0, %1" : "+v"(wpk[0]), "+v"(wpk[2]));
    asm volatile("v_permlane32_swap_b32 %0, %1" : "+v"(wpk[1]), "+v"(wpk[3]));
    asm volatile("v_permlane32_swap_b32 %0, %1" : "+v"(wpk[4]), "+v"(wpk[6]));
    asm volatile("v_permlane32_swap_b32 %0, %1" : "+v"(wpk[5]), "+v"(wpk[7]));
    union { unsigned int u[4]; bf16x8 v; } f0, f1;
    f0.u[0] = wpk[0]; f0.u[1] = wpk[1]; f0.u[2] = wpk[2]; f0.u[3] = wpk[3];
    f1.u[0] = wpk[4]; f1.u[1] = wpk[5]; f1.u[2] = wpk[6]; f1.u[3] = wpk[7];
    __builtin_amdgcn_s_setprio(1);
    o0 = __builtin_amdgcn_mfma_f32_32x32x16_bf16(f0.v, v0[0], o0, 0, 0, 0);
    o1 = __builtin_amdgcn_mfma_f32_32x32x16_bf16(f0.v, v1[0], o1, 0, 0, 0);
    o0 = __builtin_amdgcn_mfma_f32_32x32x16_bf16(f1.v, v0[1], o0, 0, 0, 0);
    o1 = __builtin_amdgcn_mfma_f32_32x32x16_bf16(f1.v, v1[1], o1, 0, 0, 0);
    __builtin_amdgcn_s_setprio(0);
  };

  int s = w;
  if (s <= c) {
    bf16x8 kfA[4], vA0[2], vA1[2], kfB[4], vB0[2], vB1[2];
    loadsub(kfA, vA0, vA1, s);
    while (s + 8 <= c) {
      loadsub(kfB, vB0, vB1, s + 4);
      compute(kfA, vA0, vA1, false);
      loadsub(kfA, vA0, vA1, s + 8);
      compute(kfB, vB0, vB1, false);
      s += 8;
    }
    if (s + 4 <= c) {
      loadsub(kfB, vB0, vB1, s + 4);
      compute(kfA, vA0, vA1, false);
      compute(kfB, vB0, vB1, (s + 4) == c);
    } else {
      compute(kfA, vA0, vA1, s == c);
    }
  }

  lsum += __shfl_xor(lsum, 32);

  if (w) {
#pragma unroll
    for (int r = 0; r < 16; ++r) Opart[w - 1][r][l] = make_float2(o0[r], o1[r]);
    if (l < 32) Lpart[w - 1][l] = lsum;
  }
  __syncthreads();
  if (w == 0) {
    float ltot = lsum + Lpart[0][ql] + Lpart[1][ql] + Lpart[2][ql];
    if (l < 32) Linv[l] = 1.0f / ltot;
#pragma unroll
    for (int r = 0; r < 16; ++r) {
      float2 t0 = Opart[0][r][l], t1 = Opart[1][r][l], t2 = Opart[2][r][l];
      o0[r] += t0.x + t1.x + t2.x;
      o1[r] += t0.y + t1.y + t2.y;
    }
#pragma unroll
    for (int r = 0; r < 16; ++r) {
      int qr = (r & 3) + 8 * (r >> 2) + 4 * hi;
      float li = Linv[qr];
      int m = b * 2048 + q0 + qr;
      // Z in A4 tiled form: [m/16][k/32][16][32], k = hd*64 (+32 for o1)
      long idx = ((long)(m >> 4) * 24 + hd * 2) * 512 + (m & 15) * 32 + ql;
      Z[idx] = f2bf(o0[r] * li);
      Z[idx + 512] = f2bf(o1[r] * li);
    }
  }
}

extern "C" void kernel_launch(void* const* d_in, const int* in_sizes, int n_in,
                              void* d_out, int out_size, void* d_ws, size_t ws_size,
                              hipStream_t stream) {
  const float* x  = (const float*)d_in[0];
  const float* wk = (const float*)d_in[1];
  const float* wq = (const float*)d_in[2];
  const float* wv = (const float*)d_in[3];
  const float* wo = (const float*)d_in[4];

  unsigned short* ws = (unsigned short*)d_ws;
  unsigned short* x4    = ws;                    // 3145728 (A4 tiled)
  unsigned short* wkqv4 = x4 + 3145728;          // 1769472 (B4 tiled, rows 0..2303)
  unsigned short* wo4   = wkqv4 + 1769472;       // 589824  (B4 tiled)
  unsigned short* qb    = wo4 + 589824;          // 3145728
  unsigned short* k4b   = qb + 3145728;          // 3145728
  unsigned short* v4b   = k4b + 3145728;         // 3145728
  unsigned short* z4b   = v4b + 3145728;         // 3145728 (A4 tiled)

  cvt_all<<<5376, 256, 0, stream>>>(x, wk, wq, wv, wo, x4, wkqv4, wo4);
  gemm_qkv<<<576, 256, 0, stream>>>(x4, wkqv4, k4b, qb, v4b);
  attn<<<1536, 256, 0, stream>>>(qb, k4b, v4b, z4b);
  gemm_out<<<192, 256, 0, stream>>>(z4b, wo4, (float*)d_out);
}

// Round 10
// 98.865 us; speedup vs baseline: 1.0229x; 1.0229x over previous
//
#include <hip/hip_runtime.h>
#include <hip/hip_bf16.h>

typedef __attribute__((ext_vector_type(8))) short bf16x8;
typedef __attribute__((ext_vector_type(4))) float f32x4;
typedef __attribute__((ext_vector_type(16))) float f32x16;

static __device__ __forceinline__ unsigned short f2bf(float f) {
  union { float f; unsigned int u; } v; v.f = f;
  unsigned int u = v.u;
  return (unsigned short)((u + 0x7FFFu + ((u >> 16) & 1u)) >> 16);
}

__device__ __forceinline__ void async_ld16(const void* g, void* l) {
  __builtin_amdgcn_global_load_lds(
      (const __attribute__((address_space(1))) unsigned int*)g,
      (__attribute__((address_space(3))) unsigned int*)l, 16, 0, 0);
}

// fp32 -> bf16 for x + W_K/W_Q/W_V/W_O; W_Q gets 0.125*log2(e) folded in
__global__ __launch_bounds__(256) void cvt_all(
    const float* __restrict__ x, const float* __restrict__ wk,
    const float* __restrict__ wq, const float* __restrict__ wv,
    const float* __restrict__ wo, unsigned short* __restrict__ dst) {
  int i = blockIdx.x * 256 + threadIdx.x;
  int e0 = i * 4;
  const float* src;
  int off;
  float scale = 1.0f;
  if (e0 < 3145728) { src = x; off = e0; }
  else {
    int j = e0 - 3145728;
    int a = j / 589824;
    off = j - a * 589824;
    src = (a == 0) ? wk : (a == 1) ? wq : (a == 2) ? wv : wo;
    if (a == 1) scale = 0.18033688011112042f;  // 0.125 * log2(e)
  }
  float4 v = *(const float4*)(src + off);
  ushort4 r;
  r.x = f2bf(v.x * scale); r.y = f2bf(v.y * scale);
  r.z = f2bf(v.z * scale); r.w = f2bf(v.w * scale);
  *(ushort4*)(dst + e0) = r;
}

// 128x128 tile GEMM, BK=32, double-buffered (2x16KB LDS) + counted vmcnt(4).
// MODE 0: fused QKV epilogue (N=2304 -> K4 tiled / qb [B,H,P,64] / V4 tiled)
// MODE 1: fp32 linear out (N=768)
template <int MODE>
__device__ __forceinline__ void gemm_body(
    const unsigned short* __restrict__ A,
    const unsigned short* __restrict__ Bt,
    void* __restrict__ outK, void* __restrict__ outQ, void* __restrict__ outV,
    int m0, int n0,
    unsigned short (*As)[4096], unsigned short (*Bs)[4096]) {
  const int tid = threadIdx.x;
  const int w = tid >> 6;
  const int l = tid & 63;
  const int g = l >> 4;
  const int c = l & 15;
  const int wr = w >> 1, wc = w & 1;

  f32x4 acc[4][4];
#pragma unroll
  for (int i = 0; i < 4; i++)
#pragma unroll
    for (int j = 0; j < 4; j++) acc[i][j] = (f32x4){0.f, 0.f, 0.f, 0.f};

  const int slotrow = l >> 2;   // 0..15
  const int slotq = l & 3;      // 16B granule within 64B row

  // stage one BK=32 K-slab: As/Bs chunk = 16 rows x 32 elems (1KB), wave w does
  // chunks {2w, 2w+1}; source col pre-swizzled so reads use q = g ^ (row&3).
  auto stage = [&](int buf, int kt) {
    const int k0 = kt * 32;
#pragma unroll
    for (int i = 0; i < 2; ++i) {
      int chunk = w * 2 + i;
      int row = chunk * 16 + slotrow;
      int gsrc = (slotq ^ (row & 3)) * 8;
      async_ld16(A + (long)(m0 + row) * 768 + k0 + gsrc, &As[buf][chunk * 512 + l * 8]);
      async_ld16(Bt + (long)(n0 + row) * 768 + k0 + gsrc, &Bs[buf][chunk * 512 + l * 8]);
    }
  };

  stage(0, 0);
  for (int kt = 0; kt < 24; ++kt) {
    const int cur = kt & 1;
    if (kt < 23) {
      stage(cur ^ 1, kt + 1);
      asm volatile("s_waitcnt vmcnt(4)" ::: "memory");
    } else {
      asm volatile("s_waitcnt vmcnt(0)" ::: "memory");
    }
    __builtin_amdgcn_sched_barrier(0);
    __builtin_amdgcn_s_barrier();
    __builtin_amdgcn_sched_barrier(0);

    bf16x8 a[4], b[4];
#pragma unroll
    for (int mi = 0; mi < 4; ++mi) {
      int row = wr * 64 + mi * 16 + c;
      a[mi] = *(const bf16x8*)&As[cur][row * 32 + ((g ^ (row & 3)) * 8)];
    }
#pragma unroll
    for (int ni = 0; ni < 4; ++ni) {
      int row = wc * 64 + ni * 16 + c;
      b[ni] = *(const bf16x8*)&Bs[cur][row * 32 + ((g ^ (row & 3)) * 8)];
    }
    __builtin_amdgcn_s_setprio(1);
#pragma unroll
    for (int mi = 0; mi < 4; ++mi)
#pragma unroll
      for (int ni = 0; ni < 4; ++ni)
        acc[mi][ni] = __builtin_amdgcn_mfma_f32_16x16x32_bf16(a[mi], b[ni], acc[mi][ni], 0, 0, 0);
    __builtin_amdgcn_s_setprio(0);

    __builtin_amdgcn_sched_barrier(0);
    asm volatile("s_waitcnt lgkmcnt(0)" ::: "memory");
    __builtin_amdgcn_s_barrier();
    __builtin_amdgcn_sched_barrier(0);
  }

  if (MODE == 1) {
    float* O = (float*)outK;
#pragma unroll
    for (int mi = 0; mi < 4; ++mi)
#pragma unroll
      for (int ni = 0; ni < 4; ++ni)
#pragma unroll
        for (int r = 0; r < 4; ++r) {
          int m = m0 + wr * 64 + mi * 16 + g * 4 + r;
          int n = n0 + wc * 64 + ni * 16 + c;
          O[(long)m * 768 + n] = acc[mi][ni][r];
        }
  } else {
    const int which = (n0 >= 1536) ? 2 : (n0 >= 768 ? 1 : 0);
    const int nb = n0 - which * 768;
#pragma unroll
    for (int mi = 0; mi < 4; ++mi)
#pragma unroll
      for (int ni = 0; ni < 4; ++ni)
#pragma unroll
        for (int r = 0; r < 4; ++r) {
          int m = m0 + wr * 64 + mi * 16 + g * 4 + r;
          int nn = nb + wc * 64 + ni * 16 + c;
          int b = m >> 11, p = m & 2047;
          int h = nn >> 6, e = nn & 63;
          unsigned short val = f2bf(acc[mi][ni][r]);
          long bh = b * 12 + h;
          if (which == 0) {
            // K4 tiled: [bh][p/32][d/16][p&31][d&15]
            long idx = bh * 131072 + (p >> 5) * 2048 + (e >> 4) * 512 + (p & 31) * 16 + (e & 15);
            ((unsigned short*)outK)[idx] = val;
          } else if (which == 1) {
            ((unsigned short*)outQ)[((bh * 2048 + p) << 6) + e] = val;
          } else {
            // V4 tiled: [bh][p/16][e][p&15]
            long idx = bh * 131072 + (p >> 4) * 1024 + e * 16 + (p & 15);
            ((unsigned short*)outV)[idx] = val;
          }
        }
  }
}

// grid 576 (1D). XCD-chunked: xcd = bid&7 owns 8m x 9n panel (3.3 MB, L2-fit)
__global__ __launch_bounds__(256) void gemm_qkv(
    const unsigned short* __restrict__ A,
    const unsigned short* __restrict__ Wkqv,   // [2304][768] = [Wk;Wq;Wv]
    unsigned short* __restrict__ k4b, unsigned short* __restrict__ qb,
    unsigned short* __restrict__ v4b) {
  __shared__ __align__(16) unsigned short As[2][4096];
  __shared__ __align__(16) unsigned short Bs[2][4096];
  const int lb = blockIdx.x;
  const int xcd = lb & 7, idx = lb >> 3;       // idx 0..71
  const int mg = xcd >> 1, ng = xcd & 1;
  const int mi = idx / 9, ni = idx - 9 * mi;   // ni fastest: share A-panel
  gemm_body<0>(A, Wkqv, k4b, qb, v4b, (mg * 8 + mi) * 128, (ng * 9 + ni) * 128, As, Bs);
}

// grid 192 (1D). xcd = bid&7 owns 4m x 6n panel
__global__ __launch_bounds__(256) void gemm_out(
    const unsigned short* __restrict__ A,
    const unsigned short* __restrict__ Bt,
    float* __restrict__ out) {
  __shared__ __align__(16) unsigned short As[2][4096];
  __shared__ __align__(16) unsigned short Bs[2][4096];
  const int lb = blockIdx.x;
  const int xcd = lb & 7, idx = lb >> 3;       // idx 0..23
  const int mi = idx / 6, ni = idx - 6 * mi;
  gemm_body<1>(A, Bt, out, nullptr, nullptr, (xcd * 4 + mi) * 128, ni * 128, As, Bs);
}

// causal flash attention: swapped QK^T (32x32x16), in-register softmax,
// split-k x4: block = 4 waves on ONE 32-row q-chunk; LPT dispatch.
// K4/V4 tiled layouts -> every fragment load is a dense 1KB wave-read.
__global__ __launch_bounds__(256) void attn(
    const unsigned short* __restrict__ Q,
    const unsigned short* __restrict__ K4,
    const unsigned short* __restrict__ V4,
    unsigned short* __restrict__ Z) {
  __shared__ float2 Opart[3][16][64];
  __shared__ float Lpart[3][32];
  __shared__ float Linv[32];
  const int bx = blockIdx.x;                   // 0..1535
  const int cidx = bx / 24;                    // 0..63
  const int bh = bx - cidx * 24;               // 0..23
  const int c = 63 - cidx;                     // LPT: big chunks dispatched first
  const int tid = threadIdx.x;
  const int w = tid >> 6;                      // kpar 0..3
  const int l = tid & 63;
  const int ql = l & 31;
  const int hi = l >> 5;
  const int b = bh / 12, hd = bh - b * 12;
  const long base = (long)bh * 2048 * 64;
  const int q0 = c * 32;

  bf16x8 qf[4];
  {
    const unsigned short* qp = Q + base + (long)(q0 + ql) * 64 + hi * 8;
#pragma unroll
    for (int d = 0; d < 4; ++d) qf[d] = *(const bf16x8*)(qp + d * 16);
  }

  f32x16 o0, o1;
#pragma unroll
  for (int r = 0; r < 16; ++r) { o0[r] = 0.f; o1[r] = 0.f; }
  float lsum = 0.f;

  const unsigned short* kp = K4 + (long)bh * 131072 + ql * 16 + hi * 8;
  const unsigned short* vp = V4 + (long)bh * 131072 + ql * 16 + hi * 8;

  auto loadsub = [&](bf16x8* kf, bf16x8* v0, bf16x8* v1, int s) {
    const unsigned short* kps = kp + (long)s * 2048;
#pragma unroll
    for (int d = 0; d < 4; ++d) kf[d] = *(const bf16x8*)(kps + d * 512);
    const unsigned short* vps = vp + (long)s * 2048;
    v0[0] = *(const bf16x8*)(vps);
    v0[1] = *(const bf16x8*)(vps + 1024);
    v1[0] = *(const bf16x8*)(vps + 512);
    v1[1] = *(const bf16x8*)(vps + 1536);
  };

  auto compute = [&](const bf16x8* kf, const bf16x8* v0, const bf16x8* v1, bool diag) {
    __builtin_amdgcn_s_setprio(1);
    f32x16 s_;
#pragma unroll
    for (int r = 0; r < 16; ++r) s_[r] = 0.f;
#pragma unroll
    for (int d = 0; d < 4; ++d)
      s_ = __builtin_amdgcn_mfma_f32_32x32x16_bf16(kf[d], qf[d], s_, 0, 0, 0);
    __builtin_amdgcn_s_setprio(0);
    if (diag) {
#pragma unroll
      for (int r = 0; r < 16; ++r) {
        int krow = (r & 3) + 8 * (r >> 2) + 4 * hi;
        s_[r] = (krow <= ql) ? s_[r] : -1e30f;
      }
    }
    float p[16];
#pragma unroll
    for (int r = 0; r < 16; ++r) { p[r] = exp2f(s_[r]); lsum += p[r]; }
    unsigned int wpk[8];
#pragma unroll
    for (int i = 0; i < 8; ++i)
      asm("v_cvt_pk_bf16_f32 %0, %1, %2" : "=v"(wpk[i]) : "v"(p[2 * i]), "v"(p[2 * i + 1]));
    asm volatile("v_permlane32_swap_b32 %0, %1" : "+v"(wpk[0]), "+v"(wpk[2]));
    asm volatile("v_permlane32_swap_b32 %0, %1" : "+v"(wpk[1]), "+v"(wpk[3]));
    asm volatile("v_permlane32_swap_b32 %0, %1" : "+v"(wpk[4]), "+v"(wpk[6]));
    asm volatile("v_permlane32_swap_b32 %0, %1" : "+v"(wpk[5]), "+v"(wpk[7]));
    union { unsigned int u[4]; bf16x8 v; } f0, f1;
    f0.u[0] = wpk[0]; f0.u[1] = wpk[1]; f0.u[2] = wpk[2]; f0.u[3] = wpk[3];
    f1.u[0] = wpk[4]; f1.u[1] = wpk[5]; f1.u[2] = wpk[6]; f1.u[3] = wpk[7];
    __builtin_amdgcn_s_setprio(1);
    o0 = __builtin_amdgcn_mfma_f32_32x32x16_bf16(f0.v, v0[0], o0, 0, 0, 0);
    o1 = __builtin_amdgcn_mfma_f32_32x32x16_bf16(f0.v, v1[0], o1, 0, 0, 0);
    o0 = __builtin_amdgcn_mfma_f32_32x32x16_bf16(f1.v, v0[1], o0, 0, 0, 0);
    o1 = __builtin_amdgcn_mfma_f32_32x32x16_bf16(f1.v, v1[1], o1, 0, 0, 0);
    __builtin_amdgcn_s_setprio(0);
  };

  int s = w;
  if (s <= c) {
    bf16x8 kfA[4], vA0[2], vA1[2], kfB[4], vB0[2], vB1[2];
    loadsub(kfA, vA0, vA1, s);
    while (s + 8 <= c) {
      loadsub(kfB, vB0, vB1, s + 4);
      compute(kfA, vA0, vA1, false);
      loadsub(kfA, vA0, vA1, s + 8);
      compute(kfB, vB0, vB1, false);
      s += 8;
    }
    if (s + 4 <= c) {
      loadsub(kfB, vB0, vB1, s + 4);
      compute(kfA, vA0, vA1, false);
      compute(kfB, vB0, vB1, (s + 4) == c);
    } else {
      compute(kfA, vA0, vA1, s == c);
    }
  }

  lsum += __shfl_xor(lsum, 32);

  if (w) {
#pragma unroll
    for (int r = 0; r < 16; ++r) Opart[w - 1][r][l] = make_float2(o0[r], o1[r]);
    if (l < 32) Lpart[w - 1][l] = lsum;
  }
  __syncthreads();
  if (w == 0) {
    float ltot = lsum + Lpart[0][ql] + Lpart[1][ql] + Lpart[2][ql];
    if (l < 32) Linv[l] = 1.0f / ltot;
#pragma unroll
    for (int r = 0; r < 16; ++r) {
      float2 t0 = Opart[0][r][l], t1 = Opart[1][r][l], t2 = Opart[2][r][l];
      o0[r] += t0.x + t1.x + t2.x;
      o1[r] += t0.y + t1.y + t2.y;
    }
#pragma unroll
    for (int r = 0; r < 16; ++r) {
      int qr = (r & 3) + 8 * (r >> 2) + 4 * hi;
      float li = Linv[qr];
      unsigned short* zp = Z + ((long)(b * 2048 + q0 + qr) * 768 + hd * 64 + ql);
      zp[0]  = f2bf(o0[r] * li);
      zp[32] = f2bf(o1[r] * li);
    }
  }
}

extern "C" void kernel_launch(void* const* d_in, const int* in_sizes, int n_in,
                              void* d_out, int out_size, void* d_ws, size_t ws_size,
                              hipStream_t stream) {
  const float* x  = (const float*)d_in[0];
  const float* wk = (const float*)d_in[1];
  const float* wq = (const float*)d_in[2];
  const float* wv = (const float*)d_in[3];
  const float* wo = (const float*)d_in[4];

  unsigned short* ws = (unsigned short*)d_ws;
  unsigned short* x_bf  = ws;                    // 3145728
  unsigned short* wk_bf = x_bf + 3145728;        // 589824 each, [Wk;Wq;Wv] contiguous
  unsigned short* wo_bf = wk_bf + 3 * 589824;
  unsigned short* qb    = wo_bf + 589824;        // 3145728 each
  unsigned short* k4b   = qb + 3145728;
  unsigned short* v4b   = k4b + 3145728;
  unsigned short* zb    = v4b + 3145728;

  cvt_all<<<5376, 256, 0, stream>>>(x, wk, wq, wv, wo, x_bf);
  gemm_qkv<<<576, 256, 0, stream>>>(x_bf, wk_bf, k4b, qb, v4b);
  attn<<<1536, 256, 0, stream>>>(qb, k4b, v4b, zb);
  gemm_out<<<192, 256, 0, stream>>>(zb, wo_bf, (float*)d_out);
}

// Round 11
// 92.649 us; speedup vs baseline: 1.0915x; 1.0671x over previous
//
#include <hip/hip_runtime.h>
#include <hip/hip_bf16.h>

typedef __attribute__((ext_vector_type(8))) short bf16x8;
typedef __attribute__((ext_vector_type(4))) float f32x4;
typedef __attribute__((ext_vector_type(16))) float f32x16;

static __device__ __forceinline__ unsigned short f2bf(float f) {
  union { float f; unsigned int u; } v; v.f = f;
  unsigned int u = v.u;
  return (unsigned short)((u + 0x7FFFu + ((u >> 16) & 1u)) >> 16);
}

__device__ __forceinline__ void async_ld16(const void* g, void* l) {
  __builtin_amdgcn_global_load_lds(
      (const __attribute__((address_space(1))) unsigned int*)g,
      (__attribute__((address_space(3))) unsigned int*)l, 16, 0, 0);
}

// fp32 -> bf16 for x + W_K/W_Q/W_V/W_O; W_Q gets 0.125*log2(e) folded in
__global__ __launch_bounds__(256) void cvt_all(
    const float* __restrict__ x, const float* __restrict__ wk,
    const float* __restrict__ wq, const float* __restrict__ wv,
    const float* __restrict__ wo, unsigned short* __restrict__ dst) {
  int i = blockIdx.x * 256 + threadIdx.x;
  int e0 = i * 4;
  const float* src;
  int off;
  float scale = 1.0f;
  if (e0 < 3145728) { src = x; off = e0; }
  else {
    int j = e0 - 3145728;
    int a = j / 589824;
    off = j - a * 589824;
    src = (a == 0) ? wk : (a == 1) ? wq : (a == 2) ? wv : wo;
    if (a == 1) scale = 0.18033688011112042f;  // 0.125 * log2(e)
  }
  float4 v = *(const float4*)(src + off);
  ushort4 r;
  r.x = f2bf(v.x * scale); r.y = f2bf(v.y * scale);
  r.z = f2bf(v.z * scale); r.w = f2bf(v.w * scale);
  *(ushort4*)(dst + e0) = r;
}

// 128x96 tile GEMM, BK=64, single-buffered LDS (28KB), m97-style loop.
// MODE 0: fused QKV epilogue (N=2304 -> K4 tiled / qb [B,H,P,64] / V4 tiled)
// MODE 1: fp32 linear out (N=768)
template <int MODE>
__device__ __forceinline__ void gemm_body(
    const unsigned short* __restrict__ A,
    const unsigned short* __restrict__ Bt,
    void* __restrict__ outK, void* __restrict__ outQ, void* __restrict__ outV,
    int m0, int n0,
    unsigned short* As, unsigned short* Bs) {
  const int tid = threadIdx.x;
  const int w = tid >> 6;
  const int l = tid & 63;
  const int g = l >> 4;
  const int c = l & 15;
  const int wr = w >> 1, wc = w & 1;

  f32x4 acc[4][3];
#pragma unroll
  for (int i = 0; i < 4; i++)
#pragma unroll
    for (int j = 0; j < 3; j++) acc[i][j] = (f32x4){0.f, 0.f, 0.f, 0.f};

  const int lrow = l >> 3;
  const int lcolx = ((l & 7) ^ lrow) * 8;

  for (int kt = 0; kt < 12; ++kt) {
    const int k0 = kt * 64;
#pragma unroll
    for (int cc = 0; cc < 4; ++cc) {
      int chunk = cc * 4 + w;                  // A: 16 chunks of 8 rows
      int row = chunk * 8 + lrow;
      async_ld16(A + (long)(m0 + row) * 768 + k0 + lcolx, &As[chunk * 512]);
    }
#pragma unroll
    for (int cc = 0; cc < 3; ++cc) {
      int chunk = cc * 4 + w;                  // B: 12 chunks of 8 rows
      int row = chunk * 8 + lrow;
      async_ld16(Bt + (long)(n0 + row) * 768 + k0 + lcolx, &Bs[chunk * 512]);
    }
    __syncthreads();
#pragma unroll
    for (int ks = 0; ks < 2; ++ks) {
      bf16x8 a[4], b[3];
#pragma unroll
      for (int mi = 0; mi < 4; ++mi) {
        int row = wr * 64 + mi * 16 + c;
        int col = (ks * 32 + g * 8) ^ ((row & 7) * 8);
        a[mi] = *(const bf16x8*)&As[row * 64 + col];
      }
#pragma unroll
      for (int ni = 0; ni < 3; ++ni) {
        int row = wc * 48 + ni * 16 + c;
        int col = (ks * 32 + g * 8) ^ ((row & 7) * 8);
        b[ni] = *(const bf16x8*)&Bs[row * 64 + col];
      }
#pragma unroll
      for (int mi = 0; mi < 4; ++mi)
#pragma unroll
        for (int ni = 0; ni < 3; ++ni)
          acc[mi][ni] = __builtin_amdgcn_mfma_f32_16x16x32_bf16(a[mi], b[ni], acc[mi][ni], 0, 0, 0);
    }
    __syncthreads();
  }

  if (MODE == 1) {
    float* O = (float*)outK;
#pragma unroll
    for (int mi = 0; mi < 4; ++mi)
#pragma unroll
      for (int ni = 0; ni < 3; ++ni)
#pragma unroll
        for (int r = 0; r < 4; ++r) {
          int m = m0 + wr * 64 + mi * 16 + g * 4 + r;
          int n = n0 + wc * 48 + ni * 16 + c;
          O[(long)m * 768 + n] = acc[mi][ni][r];
        }
  } else {
    const int which = (n0 >= 1536) ? 2 : (n0 >= 768 ? 1 : 0);
    const int nb = n0 - which * 768;
#pragma unroll
    for (int mi = 0; mi < 4; ++mi)
#pragma unroll
      for (int ni = 0; ni < 3; ++ni)
#pragma unroll
        for (int r = 0; r < 4; ++r) {
          int m = m0 + wr * 64 + mi * 16 + g * 4 + r;
          int nn = nb + wc * 48 + ni * 16 + c;
          int b = m >> 11, p = m & 2047;
          int h = nn >> 6, e = nn & 63;
          unsigned short val = f2bf(acc[mi][ni][r]);
          long bh = b * 12 + h;
          if (which == 0) {
            // K4 tiled: [bh][p/32][d/16][p&31][d&15]
            long idx = bh * 131072 + (p >> 5) * 2048 + (e >> 4) * 512 + (p & 31) * 16 + (e & 15);
            ((unsigned short*)outK)[idx] = val;
          } else if (which == 1) {
            ((unsigned short*)outQ)[((bh * 2048 + p) << 6) + e] = val;
          } else {
            // V4 tiled: [bh][p/16][e][p&15]
            long idx = bh * 131072 + (p >> 4) * 1024 + e * 16 + (p & 15);
            ((unsigned short*)outV)[idx] = val;
          }
        }
  }
}

// grid 768 (1D) = 3 blocks/CU exact. XCD-chunked: xcd = bid&7 owns
// 8m x 12n panel (A 1.57MB + B 1.77MB < 4MB L2); ni fastest shares A-tile.
__global__ __launch_bounds__(256) void gemm_qkv(
    const unsigned short* __restrict__ A,
    const unsigned short* __restrict__ Wkqv,   // [2304][768] = [Wk;Wq;Wv]
    unsigned short* __restrict__ k4b, unsigned short* __restrict__ qb,
    unsigned short* __restrict__ v4b) {
  __shared__ __align__(16) unsigned short As[128 * 64];
  __shared__ __align__(16) unsigned short Bs[96 * 64];
  const int lb = blockIdx.x;
  const int xcd = lb & 7, idx = lb >> 3;       // idx 0..95
  const int mg = xcd >> 1, ng = xcd & 1;
  const int mi = idx / 12, ni = idx - 12 * mi; // mi 0..7, ni 0..11
  gemm_body<0>(A, Wkqv, k4b, qb, v4b, (mg * 8 + mi) * 128, (ng * 12 + ni) * 96, As, Bs);
}

// grid 256 (1D) = 1 block/CU exact. xcd = bid&7 owns 4m x 8n panel.
__global__ __launch_bounds__(256) void gemm_out(
    const unsigned short* __restrict__ A,
    const unsigned short* __restrict__ Bt,
    float* __restrict__ out) {
  __shared__ __align__(16) unsigned short As[128 * 64];
  __shared__ __align__(16) unsigned short Bs[96 * 64];
  const int lb = blockIdx.x;
  const int xcd = lb & 7, idx = lb >> 3;       // idx 0..31
  const int mi = idx >> 3, ni = idx & 7;       // 4m x 8n
  gemm_body<1>(A, Bt, out, nullptr, nullptr, (xcd * 4 + mi) * 128, ni * 96, As, Bs);
}

// causal flash attention: swapped QK^T (32x32x16), in-register softmax,
// split-k x4: block = 4 waves on ONE 32-row q-chunk; LPT dispatch.
// K4/V4 tiled layouts -> every fragment load is a dense 1KB wave-read.
__global__ __launch_bounds__(256) void attn(
    const unsigned short* __restrict__ Q,
    const unsigned short* __restrict__ K4,
    const unsigned short* __restrict__ V4,
    unsigned short* __restrict__ Z) {
  __shared__ float2 Opart[3][16][64];
  __shared__ float Lpart[3][32];
  __shared__ float Linv[32];
  const int bx = blockIdx.x;                   // 0..1535
  const int cidx = bx / 24;                    // 0..63
  const int bh = bx - cidx * 24;               // 0..23
  const int c = 63 - cidx;                     // LPT: big chunks dispatched first
  const int tid = threadIdx.x;
  const int w = tid >> 6;                      // kpar 0..3
  const int l = tid & 63;
  const int ql = l & 31;
  const int hi = l >> 5;
  const int b = bh / 12, hd = bh - b * 12;
  const long base = (long)bh * 2048 * 64;
  const int q0 = c * 32;

  bf16x8 qf[4];
  {
    const unsigned short* qp = Q + base + (long)(q0 + ql) * 64 + hi * 8;
#pragma unroll
    for (int d = 0; d < 4; ++d) qf[d] = *(const bf16x8*)(qp + d * 16);
  }

  f32x16 o0, o1;
#pragma unroll
  for (int r = 0; r < 16; ++r) { o0[r] = 0.f; o1[r] = 0.f; }
  float lsum = 0.f;

  const unsigned short* kp = K4 + (long)bh * 131072 + ql * 16 + hi * 8;
  const unsigned short* vp = V4 + (long)bh * 131072 + ql * 16 + hi * 8;

  auto loadsub = [&](bf16x8* kf, bf16x8* v0, bf16x8* v1, int s) {
    const unsigned short* kps = kp + (long)s * 2048;
#pragma unroll
    for (int d = 0; d < 4; ++d) kf[d] = *(const bf16x8*)(kps + d * 512);
    const unsigned short* vps = vp + (long)s * 2048;
    v0[0] = *(const bf16x8*)(vps);
    v0[1] = *(const bf16x8*)(vps + 1024);
    v1[0] = *(const bf16x8*)(vps + 512);
    v1[1] = *(const bf16x8*)(vps + 1536);
  };

  auto compute = [&](const bf16x8* kf, const bf16x8* v0, const bf16x8* v1, bool diag) {
    __builtin_amdgcn_s_setprio(1);
    f32x16 s_;
#pragma unroll
    for (int r = 0; r < 16; ++r) s_[r] = 0.f;
#pragma unroll
    for (int d = 0; d < 4; ++d)
      s_ = __builtin_amdgcn_mfma_f32_32x32x16_bf16(kf[d], qf[d], s_, 0, 0, 0);
    __builtin_amdgcn_s_setprio(0);
    if (diag) {
#pragma unroll
      for (int r = 0; r < 16; ++r) {
        int krow = (r & 3) + 8 * (r >> 2) + 4 * hi;
        s_[r] = (krow <= ql) ? s_[r] : -1e30f;
      }
    }
    float p[16];
#pragma unroll
    for (int r = 0; r < 16; ++r) { p[r] = exp2f(s_[r]); lsum += p[r]; }
    unsigned int wpk[8];
#pragma unroll
    for (int i = 0; i < 8; ++i)
      asm("v_cvt_pk_bf16_f32 %0, %1, %2" : "=v"(wpk[i]) : "v"(p[2 * i]), "v"(p[2 * i + 1]));
    asm volatile("v_permlane32_swap_b32 %0, %1" : "+v"(wpk[0]), "+v"(wpk[2]));
    asm volatile("v_permlane32_swap_b32 %0, %1" : "+v"(wpk[1]), "+v"(wpk[3]));
    asm volatile("v_permlane32_swap_b32 %0, %1" : "+v"(wpk[4]), "+v"(wpk[6]));
    asm volatile("v_permlane32_swap_b32 %0, %1" : "+v"(wpk[5]), "+v"(wpk[7]));
    union { unsigned int u[4]; bf16x8 v; } f0, f1;
    f0.u[0] = wpk[0]; f0.u[1] = wpk[1]; f0.u[2] = wpk[2]; f0.u[3] = wpk[3];
    f1.u[0] = wpk[4]; f1.u[1] = wpk[5]; f1.u[2] = wpk[6]; f1.u[3] = wpk[7];
    __builtin_amdgcn_s_setprio(1);
    o0 = __builtin_amdgcn_mfma_f32_32x32x16_bf16(f0.v, v0[0], o0, 0, 0, 0);
    o1 = __builtin_amdgcn_mfma_f32_32x32x16_bf16(f0.v, v1[0], o1, 0, 0, 0);
    o0 = __builtin_amdgcn_mfma_f32_32x32x16_bf16(f1.v, v0[1], o0, 0, 0, 0);
    o1 = __builtin_amdgcn_mfma_f32_32x32x16_bf16(f1.v, v1[1], o1, 0, 0, 0);
    __builtin_amdgcn_s_setprio(0);
  };

  int s = w;
  if (s <= c) {
    bf16x8 kfA[4], vA0[2], vA1[2], kfB[4], vB0[2], vB1[2];
    loadsub(kfA, vA0, vA1, s);
    while (s + 8 <= c) {
      loadsub(kfB, vB0, vB1, s + 4);
      compute(kfA, vA0, vA1, false);
      loadsub(kfA, vA0, vA1, s + 8);
      compute(kfB, vB0, vB1, false);
      s += 8;
    }
    if (s + 4 <= c) {
      loadsub(kfB, vB0, vB1, s + 4);
      compute(kfA, vA0, vA1, false);
      compute(kfB, vB0, vB1, (s + 4) == c);
    } else {
      compute(kfA, vA0, vA1, s == c);
    }
  }

  lsum += __shfl_xor(lsum, 32);

  if (w) {
#pragma unroll
    for (int r = 0; r < 16; ++r) Opart[w - 1][r][l] = make_float2(o0[r], o1[r]);
    if (l < 32) Lpart[w - 1][l] = lsum;
  }
  __syncthreads();
  if (w == 0) {
    float ltot = lsum + Lpart[0][ql] + Lpart[1][ql] + Lpart[2][ql];
    if (l < 32) Linv[l] = 1.0f / ltot;
#pragma unroll
    for (int r = 0; r < 16; ++r) {
      float2 t0 = Opart[0][r][l], t1 = Opart[1][r][l], t2 = Opart[2][r][l];
      o0[r] += t0.x + t1.x + t2.x;
      o1[r] += t0.y + t1.y + t2.y;
    }
#pragma unroll
    for (int r = 0; r < 16; ++r) {
      int qr = (r & 3) + 8 * (r >> 2) + 4 * hi;
      float li = Linv[qr];
      unsigned short* zp = Z + ((long)(b * 2048 + q0 + qr) * 768 + hd * 64 + ql);
      zp[0]  = f2bf(o0[r] * li);
      zp[32] = f2bf(o1[r] * li);
    }
  }
}

extern "C" void kernel_launch(void* const* d_in, const int* in_sizes, int n_in,
                              void* d_out, int out_size, void* d_ws, size_t ws_size,
                              hipStream_t stream) {
  const float* x  = (const float*)d_in[0];
  const float* wk = (const float*)d_in[1];
  const float* wq = (const float*)d_in[2];
  const float* wv = (const float*)d_in[3];
  const float* wo = (const float*)d_in[4];

  unsigned short* ws = (unsigned short*)d_ws;
  unsigned short* x_bf  = ws;                    // 3145728
  unsigned short* wk_bf = x_bf + 3145728;        // 589824 each, [Wk;Wq;Wv] contiguous
  unsigned short* wo_bf = wk_bf + 3 * 589824;
  unsigned short* qb    = wo_bf + 589824;        // 3145728 each
  unsigned short* k4b   = qb + 3145728;
  unsigned short* v4b   = k4b + 3145728;
  unsigned short* zb    = v4b + 3145728;

  cvt_all<<<5376, 256, 0, stream>>>(x, wk, wq, wv, wo, x_bf);
  gemm_qkv<<<768, 256, 0, stream>>>(x_bf, wk_bf, k4b, qb, v4b);
  attn<<<1536, 256, 0, stream>>>(qb, k4b, v4b, zb);
  gemm_out<<<256, 256, 0, stream>>>(zb, wo_bf, (float*)d_out);
}

// Round 12
// 89.706 us; speedup vs baseline: 1.1273x; 1.0328x over previous
//
#include <hip/hip_runtime.h>
#include <hip/hip_bf16.h>

typedef __attribute__((ext_vector_type(8))) short bf16x8;
typedef __attribute__((ext_vector_type(4))) float f32x4;
typedef __attribute__((ext_vector_type(16))) float f32x16;

static __device__ __forceinline__ unsigned short f2bf(float f) {
  union { float f; unsigned int u; } v; v.f = f;
  unsigned int u = v.u;
  return (unsigned short)((u + 0x7FFFu + ((u >> 16) & 1u)) >> 16);
}

__device__ __forceinline__ void async_ld16(const void* g, void* l) {
  __builtin_amdgcn_global_load_lds(
      (const __attribute__((address_space(1))) unsigned int*)g,
      (__attribute__((address_space(3))) unsigned int*)l, 16, 0, 0);
}

// fp32 -> bf16. x -> linear x_bf; Wk/Wq/Wv -> B4-tiled wkqv4 (rows 0..2303,
// Wq scaled by 0.125*log2e); Wo -> B4-tiled wo4. B4: [m/16][k/32][16][32].
__global__ __launch_bounds__(256) void cvt_all(
    const float* __restrict__ x, const float* __restrict__ wk,
    const float* __restrict__ wq, const float* __restrict__ wv,
    const float* __restrict__ wo,
    unsigned short* __restrict__ x_bf, unsigned short* __restrict__ wkqv4,
    unsigned short* __restrict__ wo4) {
  int i = blockIdx.x * 256 + threadIdx.x;
  int e0 = i * 4;
  if (e0 < 3145728) {
    float4 v = *(const float4*)(x + e0);
    ushort4 r;
    r.x = f2bf(v.x); r.y = f2bf(v.y); r.z = f2bf(v.z); r.w = f2bf(v.w);
    *(ushort4*)(x_bf + e0) = r;
    return;
  }
  int j = e0 - 3145728;
  int a = j / 589824;
  int off = j - a * 589824;
  int nl = off / 768;
  int k = off - nl * 768;
  const float* src;
  unsigned short* dst;
  int m;
  float scale = 1.0f;
  if (a == 0)      { src = wk; m = nl;        dst = wkqv4; }
  else if (a == 1) { src = wq; m = 768 + nl;  dst = wkqv4; scale = 0.18033688011112042f; }
  else if (a == 2) { src = wv; m = 1536 + nl; dst = wkqv4; }
  else             { src = wo; m = nl;        dst = wo4; }
  float4 v = *(const float4*)(src + off);
  long idx = ((long)(m >> 4) * 24 + (k >> 5)) * 512 + (m & 15) * 32 + (k & 31);
  ushort4 r;
  r.x = f2bf(v.x * scale); r.y = f2bf(v.y * scale);
  r.z = f2bf(v.z * scale); r.w = f2bf(v.w * scale);
  *(ushort4*)(dst + idx) = r;
}

// 128x96 tile GEMM, BK=64. A: row-major, staged via dbuf LDS (2x16KB) with
// counted vmcnt (stage spans the K-step). B: B4 fragment-tiled, register-direct
// dense 1KB wave-reads from L2 (no LDS, no barrier dependency).
// MODE 0: fused QKV epilogue; MODE 1: fp32 linear out.
template <int MODE>
__device__ __forceinline__ void gemm_body(
    const unsigned short* __restrict__ A,
    const unsigned short* __restrict__ B4,
    void* __restrict__ outK, void* __restrict__ outQ, void* __restrict__ outV,
    int m0, int n0,
    unsigned short (*As)[8192]) {
  const int tid = threadIdx.x;
  const int w = tid >> 6;
  const int l = tid & 63;
  const int g = l >> 4;
  const int c = l & 15;
  const int wr = w >> 1, wc = w & 1;

  f32x4 acc[4][3];
#pragma unroll
  for (int i = 0; i < 4; i++)
#pragma unroll
    for (int j = 0; j < 3; j++) acc[i][j] = (f32x4){0.f, 0.f, 0.f, 0.f};

  const int lrow = l >> 3;
  const int lcolx = ((l & 7) ^ lrow) * 8;
  const unsigned short* pB = B4 + (long)((n0 >> 4) + wc * 3) * 12288 + c * 32 + g * 8;

  auto stageA = [&](int buf, int kt) {
    const int k0 = kt * 64;
#pragma unroll
    for (int cc = 0; cc < 4; ++cc) {
      int chunk = cc * 4 + w;                 // 16 chunks of 8 rows x 64 cols
      int row = chunk * 8 + lrow;
      async_ld16(A + (long)(m0 + row) * 768 + k0 + lcolx, &As[buf][chunk * 512]);
    }
  };

  stageA(0, 0);
  for (int kt = 0; kt < 12; ++kt) {
    const int cur = kt & 1;
    // B fragments for this K-step: 6 dense 16B/lane reads (issued FIRST)
    bf16x8 b[2][3];
#pragma unroll
    for (int ks = 0; ks < 2; ++ks)
#pragma unroll
      for (int ni = 0; ni < 3; ++ni)
        b[ks][ni] = *(const bf16x8*)(pB + (long)ni * 12288 + (kt * 2 + ks) * 512);
    __builtin_amdgcn_sched_barrier(0);
    if (kt < 11) {
      stageA(cur ^ 1, kt + 1);
      // queue: [stage_{kt}(4), B_kt(6), stage_{kt+1}(4)] -> vmcnt(4) retires
      // stage_kt + B_kt, leaves stage_{kt+1} in flight across the step.
      asm volatile("s_waitcnt vmcnt(4)" ::: "memory");
    } else {
      asm volatile("s_waitcnt vmcnt(0)" ::: "memory");
    }
    __builtin_amdgcn_sched_barrier(0);
    __builtin_amdgcn_s_barrier();
    __builtin_amdgcn_sched_barrier(0);

#pragma unroll
    for (int ks = 0; ks < 2; ++ks) {
      bf16x8 a[4];
#pragma unroll
      for (int mi = 0; mi < 4; ++mi) {
        int row = wr * 64 + mi * 16 + c;
        int col = (ks * 32 + g * 8) ^ ((row & 7) * 8);
        a[mi] = *(const bf16x8*)&As[cur][row * 64 + col];
      }
#pragma unroll
      for (int mi = 0; mi < 4; ++mi)
#pragma unroll
        for (int ni = 0; ni < 3; ++ni)
          acc[mi][ni] = __builtin_amdgcn_mfma_f32_16x16x32_bf16(a[mi], b[ks][ni], acc[mi][ni], 0, 0, 0);
    }
    __builtin_amdgcn_sched_barrier(0);
    asm volatile("s_waitcnt lgkmcnt(0)" ::: "memory");
    __builtin_amdgcn_s_barrier();
    __builtin_amdgcn_sched_barrier(0);
  }

  if (MODE == 1) {
    float* O = (float*)outK;
#pragma unroll
    for (int mi = 0; mi < 4; ++mi)
#pragma unroll
      for (int ni = 0; ni < 3; ++ni)
#pragma unroll
        for (int r = 0; r < 4; ++r) {
          int m = m0 + wr * 64 + mi * 16 + g * 4 + r;
          int n = n0 + wc * 48 + ni * 16 + c;
          O[(long)m * 768 + n] = acc[mi][ni][r];
        }
  } else {
    const int which = (n0 >= 1536) ? 2 : (n0 >= 768 ? 1 : 0);
    const int nb = n0 - which * 768;
#pragma unroll
    for (int mi = 0; mi < 4; ++mi)
#pragma unroll
      for (int ni = 0; ni < 3; ++ni)
#pragma unroll
        for (int r = 0; r < 4; ++r) {
          int m = m0 + wr * 64 + mi * 16 + g * 4 + r;
          int nn = nb + wc * 48 + ni * 16 + c;
          int b = m >> 11, p = m & 2047;
          int h = nn >> 6, e = nn & 63;
          unsigned short val = f2bf(acc[mi][ni][r]);
          long bh = b * 12 + h;
          if (which == 0) {
            // K4 tiled: [bh][p/32][d/16][p&31][d&15]
            long idx = bh * 131072 + (p >> 5) * 2048 + (e >> 4) * 512 + (p & 31) * 16 + (e & 15);
            ((unsigned short*)outK)[idx] = val;
          } else if (which == 1) {
            ((unsigned short*)outQ)[((bh * 2048 + p) << 6) + e] = val;
          } else {
            // V4 tiled: [bh][p/16][e][p&15]
            long idx = bh * 131072 + (p >> 4) * 1024 + e * 16 + (p & 15);
            ((unsigned short*)outV)[idx] = val;
          }
        }
  }
}

// grid 768 (1D) = 3 blocks/CU. XCD-chunked: xcd = bid&7 owns 8m x 12n panel.
__global__ __launch_bounds__(256) void gemm_qkv(
    const unsigned short* __restrict__ A,
    const unsigned short* __restrict__ Wkqv4,  // B4-tiled [Wk;Wq;Wv]
    unsigned short* __restrict__ k4b, unsigned short* __restrict__ qb,
    unsigned short* __restrict__ v4b) {
  __shared__ __align__(16) unsigned short As[2][8192];
  const int lb = blockIdx.x;
  const int xcd = lb & 7, idx = lb >> 3;       // idx 0..95
  const int mg = xcd >> 1, ng = xcd & 1;
  const int mi = idx / 12, ni = idx - 12 * mi; // ni fastest shares A-tile
  gemm_body<0>(A, Wkqv4, k4b, qb, v4b, (mg * 8 + mi) * 128, (ng * 12 + ni) * 96, As);
}

// grid 256 (1D) = 1 block/CU. xcd = bid&7 owns 4m x 8n panel.
__global__ __launch_bounds__(256) void gemm_out(
    const unsigned short* __restrict__ A,
    const unsigned short* __restrict__ Wo4,
    float* __restrict__ out) {
  __shared__ __align__(16) unsigned short As[2][8192];
  const int lb = blockIdx.x;
  const int xcd = lb & 7, idx = lb >> 3;       // idx 0..31
  const int mi = idx >> 3, ni = idx & 7;
  gemm_body<1>(A, Wo4, out, nullptr, nullptr, (xcd * 4 + mi) * 128, ni * 96, As);
}

// causal flash attention: swapped QK^T (32x32x16), in-register softmax,
// split-k x4: block = 4 waves on ONE 32-row q-chunk; LPT dispatch.
// K4/V4 tiled layouts -> every fragment load is a dense 1KB wave-read.
__global__ __launch_bounds__(256) void attn(
    const unsigned short* __restrict__ Q,
    const unsigned short* __restrict__ K4,
    const unsigned short* __restrict__ V4,
    unsigned short* __restrict__ Z) {
  __shared__ float2 Opart[3][16][64];
  __shared__ float Lpart[3][32];
  __shared__ float Linv[32];
  const int bx = blockIdx.x;                   // 0..1535
  const int cidx = bx / 24;                    // 0..63
  const int bh = bx - cidx * 24;               // 0..23
  const int c = 63 - cidx;                     // LPT: big chunks dispatched first
  const int tid = threadIdx.x;
  const int w = tid >> 6;                      // kpar 0..3
  const int l = tid & 63;
  const int ql = l & 31;
  const int hi = l >> 5;
  const int b = bh / 12, hd = bh - b * 12;
  const long base = (long)bh * 2048 * 64;
  const int q0 = c * 32;

  bf16x8 qf[4];
  {
    const unsigned short* qp = Q + base + (long)(q0 + ql) * 64 + hi * 8;
#pragma unroll
    for (int d = 0; d < 4; ++d) qf[d] = *(const bf16x8*)(qp + d * 16);
  }

  f32x16 o0, o1;
#pragma unroll
  for (int r = 0; r < 16; ++r) { o0[r] = 0.f; o1[r] = 0.f; }
  float lsum = 0.f;

  const unsigned short* kp = K4 + (long)bh * 131072 + ql * 16 + hi * 8;
  const unsigned short* vp = V4 + (long)bh * 131072 + ql * 16 + hi * 8;

  auto loadsub = [&](bf16x8* kf, bf16x8* v0, bf16x8* v1, int s) {
    const unsigned short* kps = kp + (long)s * 2048;
#pragma unroll
    for (int d = 0; d < 4; ++d) kf[d] = *(const bf16x8*)(kps + d * 512);
    const unsigned short* vps = vp + (long)s * 2048;
    v0[0] = *(const bf16x8*)(vps);
    v0[1] = *(const bf16x8*)(vps + 1024);
    v1[0] = *(const bf16x8*)(vps + 512);
    v1[1] = *(const bf16x8*)(vps + 1536);
  };

  auto compute = [&](const bf16x8* kf, const bf16x8* v0, const bf16x8* v1, bool diag) {
    __builtin_amdgcn_s_setprio(1);
    f32x16 s_;
#pragma unroll
    for (int r = 0; r < 16; ++r) s_[r] = 0.f;
#pragma unroll
    for (int d = 0; d < 4; ++d)
      s_ = __builtin_amdgcn_mfma_f32_32x32x16_bf16(kf[d], qf[d], s_, 0, 0, 0);
    __builtin_amdgcn_s_setprio(0);
    if (diag) {
#pragma unroll
      for (int r = 0; r < 16; ++r) {
        int krow = (r & 3) + 8 * (r >> 2) + 4 * hi;
        s_[r] = (krow <= ql) ? s_[r] : -1e30f;
      }
    }
    float p[16];
#pragma unroll
    for (int r = 0; r < 16; ++r) { p[r] = exp2f(s_[r]); lsum += p[r]; }
    unsigned int wpk[8];
#pragma unroll
    for (int i = 0; i < 8; ++i)
      asm("v_cvt_pk_bf16_f32 %0, %1, %2" : "=v"(wpk[i]) : "v"(p[2 * i]), "v"(p[2 * i + 1]));
    asm volatile("v_permlane32_swap_b32 %0, %1" : "+v"(wpk[0]), "+v"(wpk[2]));
    asm volatile("v_permlane32_swap_b32 %0, %1" : "+v"(wpk[1]), "+v"(wpk[3]));
    asm volatile("v_permlane32_swap_b32 %0, %1" : "+v"(wpk[4]), "+v"(wpk[6]));
    asm volatile("v_permlane32_swap_b32 %0, %1" : "+v"(wpk[5]), "+v"(wpk[7]));
    union { unsigned int u[4]; bf16x8 v; } f0, f1;
    f0.u[0] = wpk[0]; f0.u[1] = wpk[1]; f0.u[2] = wpk[2]; f0.u[3] = wpk[3];
    f1.u[0] = wpk[4]; f1.u[1] = wpk[5]; f1.u[2] = wpk[6]; f1.u[3] = wpk[7];
    __builtin_amdgcn_s_setprio(1);
    o0 = __builtin_amdgcn_mfma_f32_32x32x16_bf16(f0.v, v0[0], o0, 0, 0, 0);
    o1 = __builtin_amdgcn_mfma_f32_32x32x16_bf16(f0.v, v1[0], o1, 0, 0, 0);
    o0 = __builtin_amdgcn_mfma_f32_32x32x16_bf16(f1.v, v0[1], o0, 0, 0, 0);
    o1 = __builtin_amdgcn_mfma_f32_32x32x16_bf16(f1.v, v1[1], o1, 0, 0, 0);
    __builtin_amdgcn_s_setprio(0);
  };

  int s = w;
  if (s <= c) {
    bf16x8 kfA[4], vA0[2], vA1[2], kfB[4], vB0[2], vB1[2];
    loadsub(kfA, vA0, vA1, s);
    while (s + 8 <= c) {
      loadsub(kfB, vB0, vB1, s + 4);
      compute(kfA, vA0, vA1, false);
      loadsub(kfA, vA0, vA1, s + 8);
      compute(kfB, vB0, vB1, false);
      s += 8;
    }
    if (s + 4 <= c) {
      loadsub(kfB, vB0, vB1, s + 4);
      compute(kfA, vA0, vA1, false);
      compute(kfB, vB0, vB1, (s + 4) == c);
    } else {
      compute(kfA, vA0, vA1, s == c);
    }
  }

  lsum += __shfl_xor(lsum, 32);

  if (w) {
#pragma unroll
    for (int r = 0; r < 16; ++r) Opart[w - 1][r][l] = make_float2(o0[r], o1[r]);
    if (l < 32) Lpart[w - 1][l] = lsum;
  }
  __syncthreads();
  if (w == 0) {
    float ltot = lsum + Lpart[0][ql] + Lpart[1][ql] + Lpart[2][ql];
    if (l < 32) Linv[l] = 1.0f / ltot;
#pragma unroll
    for (int r = 0; r < 16; ++r) {
      float2 t0 = Opart[0][r][l], t1 = Opart[1][r][l], t2 = Opart[2][r][l];
      o0[r] += t0.x + t1.x + t2.x;
      o1[r] += t0.y + t1.y + t2.y;
    }
#pragma unroll
    for (int r = 0; r < 16; ++r) {
      int qr = (r & 3) + 8 * (r >> 2) + 4 * hi;
      float li = Linv[qr];
      unsigned short* zp = Z + ((long)(b * 2048 + q0 + qr) * 768 + hd * 64 + ql);
      zp[0]  = f2bf(o0[r] * li);
      zp[32] = f2bf(o1[r] * li);
    }
  }
}

extern "C" void kernel_launch(void* const* d_in, const int* in_sizes, int n_in,
                              void* d_out, int out_size, void* d_ws, size_t ws_size,
                              hipStream_t stream) {
  const float* x  = (const float*)d_in[0];
  const float* wk = (const float*)d_in[1];
  const float* wq = (const float*)d_in[2];
  const float* wv = (const float*)d_in[3];
  const float* wo = (const float*)d_in[4];

  unsigned short* ws = (unsigned short*)d_ws;
  unsigned short* x_bf  = ws;                    // 3145728 (row-major bf16)
  unsigned short* wkqv4 = x_bf + 3145728;        // 1769472 (B4 tiled)
  unsigned short* wo4   = wkqv4 + 1769472;       // 589824  (B4 tiled)
  unsigned short* qb    = wo4 + 589824;          // 3145728 each
  unsigned short* k4b   = qb + 3145728;
  unsigned short* v4b   = k4b + 3145728;
  unsigned short* zb    = v4b + 3145728;

  cvt_all<<<5376, 256, 0, stream>>>(x, wk, wq, wv, wo, x_bf, wkqv4, wo4);
  gemm_qkv<<<768, 256, 0, stream>>>(x_bf, wkqv4, k4b, qb, v4b);
  attn<<<1536, 256, 0, stream>>>(qb, k4b, v4b, zb);
  gemm_out<<<256, 256, 0, stream>>>(zb, wo4, (float*)d_out);
}

// Round 13
// 79.358 us; speedup vs baseline: 1.2743x; 1.1304x over previous
//
#include <hip/hip_runtime.h>
#include <hip/hip_bf16.h>

typedef __attribute__((ext_vector_type(8))) short bf16x8;
typedef __attribute__((ext_vector_type(4))) float f32x4;
typedef __attribute__((ext_vector_type(16))) float f32x16;

static __device__ __forceinline__ unsigned short f2bf(float f) {
  union { float f; unsigned int u; } v; v.f = f;
  unsigned int u = v.u;
  return (unsigned short)((u + 0x7FFFu + ((u >> 16) & 1u)) >> 16);
}

__device__ __forceinline__ void async_ld16(const void* g, void* l) {
  __builtin_amdgcn_global_load_lds(
      (const __attribute__((address_space(1))) unsigned int*)g,
      (__attribute__((address_space(3))) unsigned int*)l, 16, 0, 0);
}

// fp32 -> bf16. x -> linear x_bf; Wk/Wq/Wv -> B4-tiled wkqv4 (rows 0..2303,
// Wq scaled by 0.125*log2e); Wo -> B4-tiled wo4. B4: [m/16][k/32][16][32].
__global__ __launch_bounds__(256) void cvt_all(
    const float* __restrict__ x, const float* __restrict__ wk,
    const float* __restrict__ wq, const float* __restrict__ wv,
    const float* __restrict__ wo,
    unsigned short* __restrict__ x_bf, unsigned short* __restrict__ wkqv4,
    unsigned short* __restrict__ wo4) {
  int i = blockIdx.x * 256 + threadIdx.x;
  int e0 = i * 4;
  if (e0 < 3145728) {
    float4 v = *(const float4*)(x + e0);
    ushort4 r;
    r.x = f2bf(v.x); r.y = f2bf(v.y); r.z = f2bf(v.z); r.w = f2bf(v.w);
    *(ushort4*)(x_bf + e0) = r;
    return;
  }
  int j = e0 - 3145728;
  int a = j / 589824;
  int off = j - a * 589824;
  int nl = off / 768;
  int k = off - nl * 768;
  const float* src;
  unsigned short* dst;
  int m;
  float scale = 1.0f;
  if (a == 0)      { src = wk; m = nl;        dst = wkqv4; }
  else if (a == 1) { src = wq; m = 768 + nl;  dst = wkqv4; scale = 0.18033688011112042f; }
  else if (a == 2) { src = wv; m = 1536 + nl; dst = wkqv4; }
  else             { src = wo; m = nl;        dst = wo4; }
  float4 v = *(const float4*)(src + off);
  long idx = ((long)(m >> 4) * 24 + (k >> 5)) * 512 + (m & 15) * 32 + (k & 31);
  ushort4 r;
  r.x = f2bf(v.x * scale); r.y = f2bf(v.y * scale);
  r.z = f2bf(v.z * scale); r.w = f2bf(v.w * scale);
  *(ushort4*)(dst + idx) = r;
}

// 128x96 tile GEMM, BK=64. A: row-major, dbuf LDS (2x16KB), counted vmcnt.
// B: B4 fragment-tiled, register-direct with 1-deep prefetch (named sets).
// ONE barrier per K-step: stage(k+1) is issued AFTER the barrier, so the WAR
// on As[cur^1] (read in step k-1, rewritten by stage(k+1)) is ordered by this
// same barrier: every wave's step-(k-1) ds_reads were consumed (lgkmcnt waits
// precede its MFMA issue) before it arrives at the step-k barrier.
// vmcnt(6) at step k retires {B_k(6), stage_k(4)} leaving B_{k+1}(6) in flight.
// MODE 0: fused QKV epilogue; MODE 1: fp32 linear out.
template <int MODE>
__device__ __forceinline__ void gemm_body(
    const unsigned short* __restrict__ A,
    const unsigned short* __restrict__ B4,
    void* __restrict__ outK, void* __restrict__ outQ, void* __restrict__ outV,
    int m0, int n0,
    unsigned short (*As)[8192]) {
  const int tid = threadIdx.x;
  const int w = tid >> 6;
  const int l = tid & 63;
  const int g = l >> 4;
  const int c = l & 15;
  const int wr = w >> 1, wc = w & 1;

  f32x4 acc[4][3];
#pragma unroll
  for (int i = 0; i < 4; i++)
#pragma unroll
    for (int j = 0; j < 3; j++) acc[i][j] = (f32x4){0.f, 0.f, 0.f, 0.f};

  const int lrow = l >> 3;
  const int lcolx = ((l & 7) ^ lrow) * 8;
  const unsigned short* pB = B4 + (long)((n0 >> 4) + wc * 3) * 12288 + c * 32 + g * 8;

  auto stageA = [&](int buf, int kt) {
    const int k0 = kt * 64;
#pragma unroll
    for (int cc = 0; cc < 4; ++cc) {
      int chunk = cc * 4 + w;                 // 16 chunks of 8 rows x 64 cols
      int row = chunk * 8 + lrow;
      async_ld16(A + (long)(m0 + row) * 768 + k0 + lcolx, &As[buf][chunk * 512]);
    }
  };
  auto loadB = [&](bf16x8 (*b)[3], int kt) {
#pragma unroll
    for (int ks = 0; ks < 2; ++ks)
#pragma unroll
      for (int ni = 0; ni < 3; ++ni)
        b[ks][ni] = *(const bf16x8*)(pB + (long)ni * 12288 + (kt * 2 + ks) * 512);
  };
  auto step = [&](const bf16x8* asrc, const bf16x8 (*b)[3]) {
    // asrc unused; kept signature simple
  };

  bf16x8 b0[2][3], b1[2][3];
  stageA(0, 0);
  loadB(b0, 0);

#pragma unroll
  for (int kt = 0; kt < 12; kt += 2) {
    // ---- even step kt (buf 0, uses b0) ----
    if (kt + 1 < 12) loadB(b1, kt + 1);
    __builtin_amdgcn_sched_barrier(0);
    asm volatile("s_waitcnt vmcnt(6)" ::: "memory");
    __builtin_amdgcn_sched_barrier(0);
    __builtin_amdgcn_s_barrier();
    __builtin_amdgcn_sched_barrier(0);
    if (kt + 1 < 12) stageA(1, kt + 1);
#pragma unroll
    for (int ks = 0; ks < 2; ++ks) {
      bf16x8 a[4];
#pragma unroll
      for (int mi = 0; mi < 4; ++mi) {
        int row = wr * 64 + mi * 16 + c;
        int col = (ks * 32 + g * 8) ^ ((row & 7) * 8);
        a[mi] = *(const bf16x8*)&As[0][row * 64 + col];
      }
#pragma unroll
      for (int mi = 0; mi < 4; ++mi)
#pragma unroll
        for (int ni = 0; ni < 3; ++ni)
          acc[mi][ni] = __builtin_amdgcn_mfma_f32_16x16x32_bf16(a[mi], b0[ks][ni], acc[mi][ni], 0, 0, 0);
    }
    // ---- odd step kt+1 (buf 1, uses b1) ----
    if (kt + 2 < 12) loadB(b0, kt + 2);
    __builtin_amdgcn_sched_barrier(0);
    if (kt + 2 < 12) {
      asm volatile("s_waitcnt vmcnt(6)" ::: "memory");
    } else {
      asm volatile("s_waitcnt vmcnt(0)" ::: "memory");
    }
    __builtin_amdgcn_sched_barrier(0);
    __builtin_amdgcn_s_barrier();
    __builtin_amdgcn_sched_barrier(0);
    if (kt + 2 < 12) stageA(0, kt + 2);
#pragma unroll
    for (int ks = 0; ks < 2; ++ks) {
      bf16x8 a[4];
#pragma unroll
      for (int mi = 0; mi < 4; ++mi) {
        int row = wr * 64 + mi * 16 + c;
        int col = (ks * 32 + g * 8) ^ ((row & 7) * 8);
        a[mi] = *(const bf16x8*)&As[1][row * 64 + col];
      }
#pragma unroll
      for (int mi = 0; mi < 4; ++mi)
#pragma unroll
        for (int ni = 0; ni < 3; ++ni)
          acc[mi][ni] = __builtin_amdgcn_mfma_f32_16x16x32_bf16(a[mi], b1[ks][ni], acc[mi][ni], 0, 0, 0);
    }
  }

  if (MODE == 1) {
    float* O = (float*)outK;
#pragma unroll
    for (int mi = 0; mi < 4; ++mi)
#pragma unroll
      for (int ni = 0; ni < 3; ++ni)
#pragma unroll
        for (int r = 0; r < 4; ++r) {
          int m = m0 + wr * 64 + mi * 16 + g * 4 + r;
          int n = n0 + wc * 48 + ni * 16 + c;
          O[(long)m * 768 + n] = acc[mi][ni][r];
        }
  } else {
    const int which = (n0 >= 1536) ? 2 : (n0 >= 768 ? 1 : 0);
    const int nb = n0 - which * 768;
    const int b = m0 >> 11;                    // block-uniform
    if (which == 2) {
      // V4 tiled [bh][p/16][e][p&15]: r=0..3 contiguous in p&15 -> ushort4
#pragma unroll
      for (int mi = 0; mi < 4; ++mi)
#pragma unroll
        for (int ni = 0; ni < 3; ++ni) {
          int e = nb + wc * 48 + ni * 16 + c;
          int h = e >> 6, el = e & 63;
          long bh = b * 12 + h;
          int p0 = (m0 & 2047) + wr * 64 + mi * 16 + g * 4;
          long idx = bh * 131072 + (p0 >> 4) * 1024 + el * 16 + (p0 & 15);
          ushort4 pk;
          pk.x = f2bf(acc[mi][ni][0]); pk.y = f2bf(acc[mi][ni][1]);
          pk.z = f2bf(acc[mi][ni][2]); pk.w = f2bf(acc[mi][ni][3]);
          *(ushort4*)&((unsigned short*)outV)[idx] = pk;
        }
    } else {
#pragma unroll
      for (int mi = 0; mi < 4; ++mi)
#pragma unroll
        for (int ni = 0; ni < 3; ++ni)
#pragma unroll
          for (int r = 0; r < 4; ++r) {
            int m = m0 + wr * 64 + mi * 16 + g * 4 + r;
            int nn = nb + wc * 48 + ni * 16 + c;
            int p = m & 2047;
            int h = nn >> 6, e = nn & 63;
            unsigned short val = f2bf(acc[mi][ni][r]);
            long bh = b * 12 + h;
            if (which == 0) {
              // K4 tiled: [bh][p/32][d/16][p&31][d&15] (32B runs across lanes)
              long idx = bh * 131072 + (p >> 5) * 2048 + (e >> 4) * 512 + (p & 31) * 16 + (e & 15);
              ((unsigned short*)outK)[idx] = val;
            } else {
              ((unsigned short*)outQ)[((bh * 2048 + p) << 6) + e] = val;
            }
          }
    }
  }
}

// grid 768 (1D) = 3 blocks/CU. XCD-chunked: xcd = bid&7 owns 8m x 12n panel.
__global__ __launch_bounds__(256) void gemm_qkv(
    const unsigned short* __restrict__ A,
    const unsigned short* __restrict__ Wkqv4,  // B4-tiled [Wk;Wq;Wv]
    unsigned short* __restrict__ k4b, unsigned short* __restrict__ qb,
    unsigned short* __restrict__ v4b) {
  __shared__ __align__(16) unsigned short As[2][8192];
  const int lb = blockIdx.x;
  const int xcd = lb & 7, idx = lb >> 3;       // idx 0..95
  const int mg = xcd >> 1, ng = xcd & 1;
  const int mi = idx / 12, ni = idx - 12 * mi; // ni fastest shares A-tile
  gemm_body<0>(A, Wkqv4, k4b, qb, v4b, (mg * 8 + mi) * 128, (ng * 12 + ni) * 96, As);
}

// grid 256 (1D) = 1 block/CU. xcd = bid&7 owns 4m x 8n panel.
__global__ __launch_bounds__(256) void gemm_out(
    const unsigned short* __restrict__ A,
    const unsigned short* __restrict__ Wo4,
    float* __restrict__ out) {
  __shared__ __align__(16) unsigned short As[2][8192];
  const int lb = blockIdx.x;
  const int xcd = lb & 7, idx = lb >> 3;       // idx 0..31
  const int mi = idx >> 3, ni = idx & 7;
  gemm_body<1>(A, Wo4, out, nullptr, nullptr, (xcd * 4 + mi) * 128, ni * 96, As);
}

// causal flash attention: swapped QK^T (32x32x16), in-register softmax,
// split-k x4: block = 4 waves on ONE 32-row q-chunk; LPT dispatch.
// K4/V4 tiled layouts -> every fragment load is a dense 1KB wave-read.
__global__ __launch_bounds__(256) void attn(
    const unsigned short* __restrict__ Q,
    const unsigned short* __restrict__ K4,
    const unsigned short* __restrict__ V4,
    unsigned short* __restrict__ Z) {
  __shared__ float2 Opart[3][16][64];
  __shared__ float Lpart[3][32];
  __shared__ float Linv[32];
  const int bx = blockIdx.x;                   // 0..1535
  const int cidx = bx / 24;                    // 0..63
  const int bh = bx - cidx * 24;               // 0..23
  const int c = 63 - cidx;                     // LPT: big chunks dispatched first
  const int tid = threadIdx.x;
  const int w = tid >> 6;                      // kpar 0..3
  const int l = tid & 63;
  const int ql = l & 31;
  const int hi = l >> 5;
  const int b = bh / 12, hd = bh - b * 12;
  const long base = (long)bh * 2048 * 64;
  const int q0 = c * 32;

  bf16x8 qf[4];
  {
    const unsigned short* qp = Q + base + (long)(q0 + ql) * 64 + hi * 8;
#pragma unroll
    for (int d = 0; d < 4; ++d) qf[d] = *(const bf16x8*)(qp + d * 16);
  }

  f32x16 o0, o1;
#pragma unroll
  for (int r = 0; r < 16; ++r) { o0[r] = 0.f; o1[r] = 0.f; }
  float lsum = 0.f;

  const unsigned short* kp = K4 + (long)bh * 131072 + ql * 16 + hi * 8;
  const unsigned short* vp = V4 + (long)bh * 131072 + ql * 16 + hi * 8;

  auto loadsub = [&](bf16x8* kf, bf16x8* v0, bf16x8* v1, int s) {
    const unsigned short* kps = kp + (long)s * 2048;
#pragma unroll
    for (int d = 0; d < 4; ++d) kf[d] = *(const bf16x8*)(kps + d * 512);
    const unsigned short* vps = vp + (long)s * 2048;
    v0[0] = *(const bf16x8*)(vps);
    v0[1] = *(const bf16x8*)(vps + 1024);
    v1[0] = *(const bf16x8*)(vps + 512);
    v1[1] = *(const bf16x8*)(vps + 1536);
  };

  auto compute = [&](const bf16x8* kf, const bf16x8* v0, const bf16x8* v1, bool diag) {
    __builtin_amdgcn_s_setprio(1);
    f32x16 s_;
#pragma unroll
    for (int r = 0; r < 16; ++r) s_[r] = 0.f;
#pragma unroll
    for (int d = 0; d < 4; ++d)
      s_ = __builtin_amdgcn_mfma_f32_32x32x16_bf16(kf[d], qf[d], s_, 0, 0, 0);
    __builtin_amdgcn_s_setprio(0);
    if (diag) {
#pragma unroll
      for (int r = 0; r < 16; ++r) {
        int krow = (r & 3) + 8 * (r >> 2) + 4 * hi;
        s_[r] = (krow <= ql) ? s_[r] : -1e30f;
      }
    }
    float p[16];
#pragma unroll
    for (int r = 0; r < 16; ++r) { p[r] = exp2f(s_[r]); lsum += p[r]; }
    unsigned int wpk[8];
#pragma unroll
    for (int i = 0; i < 8; ++i)
      asm("v_cvt_pk_bf16_f32 %0, %1, %2" : "=v"(wpk[i]) : "v"(p[2 * i]), "v"(p[2 * i + 1]));
    asm volatile("v_permlane32_swap_b32 %0, %1" : "+v"(wpk[0]), "+v"(wpk[2]));
    asm volatile("v_permlane32_swap_b32 %0, %1" : "+v"(wpk[1]), "+v"(wpk[3]));
    asm volatile("v_permlane32_swap_b32 %0, %1" : "+v"(wpk[4]), "+v"(wpk[6]));
    asm volatile("v_permlane32_swap_b32 %0, %1" : "+v"(wpk[5]), "+v"(wpk[7]));
    union { unsigned int u[4]; bf16x8 v; } f0, f1;
    f0.u[0] = wpk[0]; f0.u[1] = wpk[1]; f0.u[2] = wpk[2]; f0.u[3] = wpk[3];
    f1.u[0] = wpk[4]; f1.u[1] = wpk[5]; f1.u[2] = wpk[6]; f1.u[3] = wpk[7];
    __builtin_amdgcn_s_setprio(1);
    o0 = __builtin_amdgcn_mfma_f32_32x32x16_bf16(f0.v, v0[0], o0, 0, 0, 0);
    o1 = __builtin_amdgcn_mfma_f32_32x32x16_bf16(f0.v, v1[0], o1, 0, 0, 0);
    o0 = __builtin_amdgcn_mfma_f32_32x32x16_bf16(f1.v, v0[1], o0, 0, 0, 0);
    o1 = __builtin_amdgcn_mfma_f32_32x32x16_bf16(f1.v, v1[1], o1, 0, 0, 0);
    __builtin_amdgcn_s_setprio(0);
  };

  int s = w;
  if (s <= c) {
    bf16x8 kfA[4], vA0[2], vA1[2], kfB[4], vB0[2], vB1[2];
    loadsub(kfA, vA0, vA1, s);
    while (s + 8 <= c) {
      loadsub(kfB, vB0, vB1, s + 4);
      compute(kfA, vA0, vA1, false);
      loadsub(kfA, vA0, vA1, s + 8);
      compute(kfB, vB0, vB1, false);
      s += 8;
    }
    if (s + 4 <= c) {
      loadsub(kfB, vB0, vB1, s + 4);
      compute(kfA, vA0, vA1, false);
      compute(kfB, vB0, vB1, (s + 4) == c);
    } else {
      compute(kfA, vA0, vA1, s == c);
    }
  }

  lsum += __shfl_xor(lsum, 32);

  if (w) {
#pragma unroll
    for (int r = 0; r < 16; ++r) Opart[w - 1][r][l] = make_float2(o0[r], o1[r]);
    if (l < 32) Lpart[w - 1][l] = lsum;
  }
  __syncthreads();
  if (w == 0) {
    float ltot = lsum + Lpart[0][ql] + Lpart[1][ql] + Lpart[2][ql];
    if (l < 32) Linv[l] = 1.0f / ltot;
#pragma unroll
    for (int r = 0; r < 16; ++r) {
      float2 t0 = Opart[0][r][l], t1 = Opart[1][r][l], t2 = Opart[2][r][l];
      o0[r] += t0.x + t1.x + t2.x;
      o1[r] += t0.y + t1.y + t2.y;
    }
#pragma unroll
    for (int r = 0; r < 16; ++r) {
      int qr = (r & 3) + 8 * (r >> 2) + 4 * hi;
      float li = Linv[qr];
      unsigned short* zp = Z + ((long)(b * 2048 + q0 + qr) * 768 + hd * 64 + ql);
      zp[0]  = f2bf(o0[r] * li);
      zp[32] = f2bf(o1[r] * li);
    }
  }
}

extern "C" void kernel_launch(void* const* d_in, const int* in_sizes, int n_in,
                              void* d_out, int out_size, void* d_ws, size_t ws_size,
                              hipStream_t stream) {
  const float* x  = (const float*)d_in[0];
  const float* wk = (const float*)d_in[1];
  const float* wq = (const float*)d_in[2];
  const float* wv = (const float*)d_in[3];
  const float* wo = (const float*)d_in[4];

  unsigned short* ws = (unsigned short*)d_ws;
  unsigned short* x_bf  = ws;                    // 3145728 (row-major bf16)
  unsigned short* wkqv4 = x_bf + 3145728;        // 1769472 (B4 tiled)
  unsigned short* wo4   = wkqv4 + 1769472;       // 589824  (B4 tiled)
  unsigned short* qb    = wo4 + 589824;          // 3145728 each
  unsigned short* k4b   = qb + 3145728;
  unsigned short* v4b   = k4b + 3145728;
  unsigned short* zb    = v4b + 3145728;

  cvt_all<<<5376, 256, 0, stream>>>(x, wk, wq, wv, wo, x_bf, wkqv4, wo4);
  gemm_qkv<<<768, 256, 0, stream>>>(x_bf, wkqv4, k4b, qb, v4b);
  attn<<<1536, 256, 0, stream>>>(qb, k4b, v4b, zb);
  gemm_out<<<256, 256, 0, stream>>>(zb, wo4, (float*)d_out);
}